// Round 1
// baseline (869.724 us; speedup 1.0000x reference)
//
#include <hip/hip_runtime.h>

#define NUM_TOKENS 8192
#define DIM 2048
#define NE 8
#define BM 128
#define BN 128
#define BK 64

typedef __bf16 bf16x8 __attribute__((ext_vector_type(8)));
typedef float f32x4 __attribute__((ext_vector_type(4)));

typedef __attribute__((address_space(1))) const void* as1_cvp;
typedef __attribute__((address_space(3))) void* as3_vp;

// fp32 -> bf16 round-to-nearest-even (manual; inputs are finite)
__device__ __forceinline__ unsigned short f2bf(float f) {
  unsigned int u = __float_as_uint(f);
  unsigned int lsb = (u >> 16) & 1u;
  u += 0x7fffu + lsb;
  return (unsigned short)(u >> 16);
}

// ---------------- expert weights fp32 -> bf16 ----------------
__global__ __launch_bounds__(256) void convert_w_kernel(
    const float4* __restrict__ w, ushort4* __restrict__ wb) {
  int i = blockIdx.x * 256 + threadIdx.x;  // grid covers 16384*2048/4 exactly
  float4 v = w[i];
  ushort4 o;
  o.x = f2bf(v.x); o.y = f2bf(v.y); o.z = f2bf(v.z); o.w = f2bf(v.w);
  wb[i] = o;
}

// -------- gating (fp32) + x fp32->bf16 + routing lists --------
__global__ __launch_bounds__(256) void gating_kernel(
    const float* __restrict__ x, const float* __restrict__ gw,
    const float* __restrict__ gb, unsigned short* __restrict__ xb,
    float* __restrict__ probs, int* __restrict__ lists,
    int* __restrict__ counts) {
  const int wave = threadIdx.x >> 6;
  const int lane = threadIdx.x & 63;
  const int t = blockIdx.x * 4 + wave;  // one wave per token
  const float4* xrow = (const float4*)(x + (size_t)t * DIM);
  ushort4* xbrow = (ushort4*)(xb + (size_t)t * DIM);
  float acc[NE];
#pragma unroll
  for (int e = 0; e < NE; ++e) acc[e] = 0.f;
#pragma unroll
  for (int it = 0; it < DIM / (4 * 64); ++it) {  // 8 iters
    const int k4 = it * 64 + lane;
    float4 xv = xrow[k4];
    ushort4 o;
    o.x = f2bf(xv.x); o.y = f2bf(xv.y); o.z = f2bf(xv.z); o.w = f2bf(xv.w);
    xbrow[k4] = o;
#pragma unroll
    for (int e = 0; e < NE; ++e) {
      float4 wv = ((const float4*)(gw + (size_t)e * DIM))[k4];
      acc[e] += xv.x * wv.x + xv.y * wv.y + xv.z * wv.z + xv.w * wv.w;
    }
  }
#pragma unroll
  for (int e = 0; e < NE; ++e) {
#pragma unroll
    for (int off = 32; off > 0; off >>= 1)
      acc[e] += __shfl_xor(acc[e], off, 64);
  }
  if (lane == 0) {
    float p[NE];
    float mx = -1e30f;
#pragma unroll
    for (int e = 0; e < NE; ++e) {
      p[e] = acc[e] + gb[e];
      mx = fmaxf(mx, p[e]);
    }
    float s = 0.f;
#pragma unroll
    for (int e = 0; e < NE; ++e) { p[e] = __expf(p[e] - mx); s += p[e]; }
    float inv = 1.f / s;
#pragma unroll
    for (int e = 0; e < NE; ++e) p[e] *= inv;
    // top-2, ties -> lower index (matches lax.top_k)
    int e0 = 0;
#pragma unroll
    for (int e = 1; e < NE; ++e) if (p[e] > p[e0]) e0 = e;
    int e1 = (e0 == 0) ? 1 : 0;
#pragma unroll
    for (int e = 0; e < NE; ++e) if (e != e0 && p[e] > p[e1]) e1 = e;
    probs[t * 2 + 0] = p[e0];
    probs[t * 2 + 1] = p[e1];
    int pos0 = atomicAdd(&counts[e0], 1);
    lists[e0 * NUM_TOKENS + pos0] = t;             // slot 0
    int pos1 = atomicAdd(&counts[e1], 1);
    lists[e1 * NUM_TOKENS + pos1] = t | 0x10000;   // slot 1
  }
}

// -------- grouped expert GEMM: out[tok] += p * (x[tok] @ W_e^T + b_e) --------
__global__ __launch_bounds__(256) void moe_gemm_kernel(
    const unsigned short* __restrict__ xb,   // [8192,2048] bf16
    const unsigned short* __restrict__ wb,   // [16384,2048] bf16
    const float* __restrict__ eb,            // [16384]
    const float* __restrict__ probs,         // [8192,2]
    const int* __restrict__ lists,           // [8,8192]
    const int* __restrict__ counts,          // [8]
    float* __restrict__ out) {               // [8192,2048]
  const int e = blockIdx.z;
  const int cnt = counts[e];
  const int m0 = blockIdx.y * BM;
  if (m0 >= cnt) return;
  const int n0 = blockIdx.x * BN;

  __shared__ __attribute__((aligned(16))) unsigned short As[BM * BK];
  __shared__ __attribute__((aligned(16))) unsigned short Bs[BN * BK];

  const int tid = threadIdx.x;
  const int wave = tid >> 6;
  const int lane = tid & 63;
  const int srow = lane >> 3;       // 0..7 row within an 8-row staging chunk
  const int scol = (lane & 7) * 8;  // element col, 16B per lane

  // per-wave staging rows: wave*32 + i*8 + srow (A gathers tokens, B is dense)
  const unsigned short* ag[4];
  const unsigned short* bg[4];
#pragma unroll
  for (int i = 0; i < 4; ++i) {
    int r = m0 + wave * 32 + i * 8 + srow;
    int rc = r < cnt ? r : cnt - 1;  // clamp: garbage rows never stored
    int tok = lists[e * NUM_TOKENS + rc] & 0xFFFF;
    ag[i] = xb + (size_t)tok * DIM + scol;
    int wr = e * DIM + n0 + wave * 32 + i * 8 + srow;
    bg[i] = wb + (size_t)wr * DIM + scol;
  }

  const f32x4 zero = {0.f, 0.f, 0.f, 0.f};
  f32x4 acc[4][4];
#pragma unroll
  for (int a = 0; a < 4; ++a)
#pragma unroll
    for (int b = 0; b < 4; ++b) acc[a][b] = zero;

  const int wm = (wave >> 1) * 64;  // wave's 64x64 quadrant
  const int wn = (wave & 1) * 64;
  const int frow = lane & 15;       // MFMA A/B operand row/col
  const int fk = (lane >> 4) * 8;   // MFMA k offset

  for (int k0 = 0; k0 < DIM; k0 += BK) {
    __syncthreads();
#pragma unroll
    for (int i = 0; i < 4; ++i) {
      __builtin_amdgcn_global_load_lds(
          (as1_cvp)(ag[i] + k0),
          (as3_vp)(As + (wave * 32 + i * 8) * BK), 16, 0, 0);
      __builtin_amdgcn_global_load_lds(
          (as1_cvp)(bg[i] + k0),
          (as3_vp)(Bs + (wave * 32 + i * 8) * BK), 16, 0, 0);
    }
    __syncthreads();  // compiler drains vmcnt before s_barrier
#pragma unroll
    for (int kk = 0; kk < BK; kk += 32) {
      bf16x8 af[4], bfr[4];
#pragma unroll
      for (int im = 0; im < 4; ++im)
        af[im] = *(const bf16x8*)(As + (wm + im * 16 + frow) * BK + kk + fk);
#pragma unroll
      for (int in_ = 0; in_ < 4; ++in_)
        bfr[in_] = *(const bf16x8*)(Bs + (wn + in_ * 16 + frow) * BK + kk + fk);
#pragma unroll
      for (int im = 0; im < 4; ++im)
#pragma unroll
        for (int in_ = 0; in_ < 4; ++in_)
          acc[im][in_] = __builtin_amdgcn_mfma_f32_16x16x32_bf16(
              af[im], bfr[in_], acc[im][in_], 0, 0, 0);
    }
  }

  // epilogue: C/D layout col=lane&15, row=quad*4+reg (m89/m91-verified)
  const int quad = lane >> 4;
  const int col = lane & 15;
#pragma unroll
  for (int im = 0; im < 4; ++im) {
#pragma unroll
    for (int reg = 0; reg < 4; ++reg) {
      int r = m0 + wm + im * 16 + quad * 4 + reg;
      if (r >= cnt) continue;
      int entry = lists[e * NUM_TOKENS + r];
      int tok = entry & 0xFFFF;
      int slot = entry >> 16;
      float p = probs[tok * 2 + slot];
      float* orow = out + (size_t)tok * DIM;
#pragma unroll
      for (int in_ = 0; in_ < 4; ++in_) {
        int n = n0 + wn + in_ * 16 + col;
        float v = acc[im][in_][reg] + eb[e * DIM + n];
        atomicAdd(orow + n, p * v);  // exactly 2 adders per element
      }
    }
  }
}

extern "C" void kernel_launch(void* const* d_in, const int* in_sizes, int n_in,
                              void* d_out, int out_size, void* d_ws, size_t ws_size,
                              hipStream_t stream) {
  const float* x  = (const float*)d_in[0];  // [8192,2048]
  const float* ew = (const float*)d_in[1];  // [16384,2048]
  const float* eb = (const float*)d_in[2];  // [16384]
  const float* gw = (const float*)d_in[3];  // [8,2048]
  const float* gb = (const float*)d_in[4];  // [8]
  float* out = (float*)d_out;               // [8192,2048] fp32
  char* ws = (char*)d_ws;

  // workspace layout (needs ~96.4 MB)
  unsigned short* wb = (unsigned short*)(ws);              // 67108864 B: W bf16
  unsigned short* xb = (unsigned short*)(ws + 67108864);   // 33554432 B: x bf16
  float* probs = (float*)(ws + 100663296);                 //    65536 B: [8192,2]
  int* lists   = (int*)(ws + 100728832);                   //   262144 B: [8,8192]
  int* counts  = (int*)(ws + 100990976);                   //       32 B

  hipMemsetAsync(counts, 0, NE * sizeof(int), stream);
  hipMemsetAsync(out, 0, (size_t)NUM_TOKENS * DIM * sizeof(float), stream);
  convert_w_kernel<<<(NE * DIM * DIM / 4) / 256, 256, 0, stream>>>(
      (const float4*)ew, (ushort4*)wb);
  gating_kernel<<<NUM_TOKENS / 4, 256, 0, stream>>>(x, gw, gb, xb, probs, lists,
                                                    counts);
  moe_gemm_kernel<<<dim3(DIM / BN, NUM_TOKENS / BM, NE), 256, 0, stream>>>(
      xb, wb, eb, probs, lists, counts, out);
}

// Round 2
// 677.791 us; speedup vs baseline: 1.2832x; 1.2832x over previous
//
#include <hip/hip_runtime.h>

#define NUM_TOKENS 8192
#define DIM 2048
#define NE 8
#define BM 128
#define BN 128
#define BK 64

typedef __bf16 bf16x8 __attribute__((ext_vector_type(8)));
typedef float f32x4 __attribute__((ext_vector_type(4)));

typedef __attribute__((address_space(1))) const void* as1_cvp;
typedef __attribute__((address_space(3))) void* as3_vp;

// fp32 -> bf16 round-to-nearest-even (manual; inputs are finite)
__device__ __forceinline__ unsigned short f2bf(float f) {
  unsigned int u = __float_as_uint(f);
  unsigned int lsb = (u >> 16) & 1u;
  u += 0x7fffu + lsb;
  return (unsigned short)(u >> 16);
}

// ---------------- expert weights fp32 -> bf16 ----------------
__global__ __launch_bounds__(256) void convert_w_kernel(
    const float4* __restrict__ w, ushort4* __restrict__ wb) {
  int i = blockIdx.x * 256 + threadIdx.x;  // grid covers 16384*2048/4 exactly
  float4 v = w[i];
  ushort4 o;
  o.x = f2bf(v.x); o.y = f2bf(v.y); o.z = f2bf(v.z); o.w = f2bf(v.w);
  wb[i] = o;
}

// -------- gating (fp32) + x fp32->bf16; NO atomics (writes routed[t]) -------
__global__ __launch_bounds__(256) void gating_kernel(
    const float* __restrict__ x, const float* __restrict__ gw,
    const float* __restrict__ gb, unsigned short* __restrict__ xb,
    float* __restrict__ probs, int* __restrict__ routed) {
  const int wave = threadIdx.x >> 6;
  const int lane = threadIdx.x & 63;
  const int t = blockIdx.x * 4 + wave;  // one wave per token
  const float4* xrow = (const float4*)(x + (size_t)t * DIM);
  ushort4* xbrow = (ushort4*)(xb + (size_t)t * DIM);
  float acc[NE];
#pragma unroll
  for (int e = 0; e < NE; ++e) acc[e] = 0.f;
#pragma unroll
  for (int it = 0; it < DIM / (4 * 64); ++it) {  // 8 iters
    const int k4 = it * 64 + lane;
    float4 xv = xrow[k4];
    ushort4 o;
    o.x = f2bf(xv.x); o.y = f2bf(xv.y); o.z = f2bf(xv.z); o.w = f2bf(xv.w);
    xbrow[k4] = o;
#pragma unroll
    for (int e = 0; e < NE; ++e) {
      float4 wv = ((const float4*)(gw + (size_t)e * DIM))[k4];
      acc[e] += xv.x * wv.x + xv.y * wv.y + xv.z * wv.z + xv.w * wv.w;
    }
  }
#pragma unroll
  for (int e = 0; e < NE; ++e) {
#pragma unroll
    for (int off = 32; off > 0; off >>= 1)
      acc[e] += __shfl_xor(acc[e], off, 64);
  }
  if (lane == 0) {
    float p[NE];
    float mx = -1e30f;
#pragma unroll
    for (int e = 0; e < NE; ++e) {
      p[e] = acc[e] + gb[e];
      mx = fmaxf(mx, p[e]);
    }
    float s = 0.f;
#pragma unroll
    for (int e = 0; e < NE; ++e) { p[e] = __expf(p[e] - mx); s += p[e]; }
    float inv = 1.f / s;
#pragma unroll
    for (int e = 0; e < NE; ++e) p[e] *= inv;
    // top-2, ties -> lower index (matches lax.top_k)
    int e0 = 0;
#pragma unroll
    for (int e = 1; e < NE; ++e) if (p[e] > p[e0]) e0 = e;
    int e1 = (e0 == 0) ? 1 : 0;
#pragma unroll
    for (int e = 0; e < NE; ++e) if (e != e0 && p[e] > p[e1]) e1 = e;
    probs[t * 2 + 0] = p[e0];
    probs[t * 2 + 1] = p[e1];
    routed[t] = e0 | (e1 << 8);
  }
}

// ---- build per-expert token lists: 8 blocks, deterministic LDS scan --------
__global__ __launch_bounds__(256) void build_lists_kernel(
    const int* __restrict__ routed, int* __restrict__ lists,
    int* __restrict__ counts) {
  const int e = blockIdx.x;
  const int tid = threadIdx.x;
  __shared__ int sc[256];
  const int base = tid * (NUM_TOKENS / 256);  // 32 tokens/thread
  int c = 0;
#pragma unroll 4
  for (int j = 0; j < NUM_TOKENS / 256; ++j) {
    int r = routed[base + j];
    c += ((r & 0xff) == e) + (((r >> 8) & 0xff) == e);
  }
  sc[tid] = c;
  __syncthreads();
  for (int ofs = 1; ofs < 256; ofs <<= 1) {  // inclusive Hillis-Steele scan
    int v = (tid >= ofs) ? sc[tid - ofs] : 0;
    __syncthreads();
    sc[tid] += v;
    __syncthreads();
  }
  int pos = sc[tid] - c;
#pragma unroll 4
  for (int j = 0; j < NUM_TOKENS / 256; ++j) {
    int t = base + j;
    int r = routed[t];
    if ((r & 0xff) == e) lists[e * NUM_TOKENS + pos++] = t;            // slot 0
    if (((r >> 8) & 0xff) == e) lists[e * NUM_TOKENS + pos++] = t | 0x10000;
  }
  if (tid == 255) counts[e] = sc[255];
}

// -------- grouped expert GEMM: out[tok] += p * (x[tok] @ W_e^T + b_e) --------
// LDS layout XOR-swizzled at 16B-granule level: granule (row, c^(row&7))
// holds global chunk c -> fragment reads spread across all 32 banks.
__global__ __launch_bounds__(256) void moe_gemm_kernel(
    const unsigned short* __restrict__ xb,   // [8192,2048] bf16
    const unsigned short* __restrict__ wb,   // [16384,2048] bf16
    const float* __restrict__ eb,            // [16384]
    const float* __restrict__ probs,         // [8192,2]
    const int* __restrict__ lists,           // [8,8192]
    const int* __restrict__ counts,          // [8]
    float* __restrict__ out) {               // [8192,2048]
  const int e = blockIdx.z;
  const int cnt = counts[e];
  const int m0 = blockIdx.y * BM;
  if (m0 >= cnt) return;
  const int n0 = blockIdx.x * BN;

  __shared__ __attribute__((aligned(16))) unsigned short As[BM * BK];
  __shared__ __attribute__((aligned(16))) unsigned short Bs[BN * BK];

  const int tid = threadIdx.x;
  const int wave = tid >> 6;
  const int lane = tid & 63;
  const int srow = lane >> 3;                       // 0..7 staging row in chunk
  const int scol = ((lane & 7) ^ srow) * 8;         // swizzled 16B-granule col

  // per-wave staging rows: wave*32 + i*8 + srow (A gathers tokens, B dense)
  const unsigned short* ag[4];
  const unsigned short* bg[4];
#pragma unroll
  for (int i = 0; i < 4; ++i) {
    int r = m0 + wave * 32 + i * 8 + srow;
    int rc = r < cnt ? r : cnt - 1;  // clamp: garbage rows never stored
    int tok = lists[e * NUM_TOKENS + rc] & 0xFFFF;
    ag[i] = xb + (size_t)tok * DIM + scol;
    int wr = e * DIM + n0 + wave * 32 + i * 8 + srow;
    bg[i] = wb + (size_t)wr * DIM + scol;
  }

  const f32x4 zero = {0.f, 0.f, 0.f, 0.f};
  f32x4 acc[4][4];
#pragma unroll
  for (int a = 0; a < 4; ++a)
#pragma unroll
    for (int b = 0; b < 4; ++b) acc[a][b] = zero;

  const int wm = (wave >> 1) * 64;  // wave's 64x64 quadrant
  const int wn = (wave & 1) * 64;
  const int frow = lane & 15;       // MFMA A/B operand row/col
  const int csel = lane >> 4;       // granule select within k-slab (0..3)
  const int swz = lane & 7;         // == row&7 for this lane's fragment rows

  for (int k0 = 0; k0 < DIM; k0 += BK) {
    __syncthreads();
#pragma unroll
    for (int i = 0; i < 4; ++i) {
      __builtin_amdgcn_global_load_lds(
          (as1_cvp)(ag[i] + k0),
          (as3_vp)(As + (wave * 32 + i * 8) * BK), 16, 0, 0);
      __builtin_amdgcn_global_load_lds(
          (as1_cvp)(bg[i] + k0),
          (as3_vp)(Bs + (wave * 32 + i * 8) * BK), 16, 0, 0);
    }
    __syncthreads();  // compiler drains vmcnt before s_barrier
#pragma unroll
    for (int kk = 0; kk < BK; kk += 32) {
      const int koff = ((((kk >> 3) | csel) ^ swz) << 3);  // swizzled element
      bf16x8 af[4], bfr[4];
#pragma unroll
      for (int im = 0; im < 4; ++im)
        af[im] = *(const bf16x8*)(As + (wm + im * 16 + frow) * BK + koff);
#pragma unroll
      for (int in_ = 0; in_ < 4; ++in_)
        bfr[in_] = *(const bf16x8*)(Bs + (wn + in_ * 16 + frow) * BK + koff);
#pragma unroll
      for (int im = 0; im < 4; ++im)
#pragma unroll
        for (int in_ = 0; in_ < 4; ++in_)
          acc[im][in_] = __builtin_amdgcn_mfma_f32_16x16x32_bf16(
              af[im], bfr[in_], acc[im][in_], 0, 0, 0);
    }
  }

  // epilogue: C/D layout col=lane&15, row=quad*4+reg (m89/m91-verified)
  const int quad = lane >> 4;
  const int col = lane & 15;
#pragma unroll
  for (int im = 0; im < 4; ++im) {
#pragma unroll
    for (int reg = 0; reg < 4; ++reg) {
      int r = m0 + wm + im * 16 + quad * 4 + reg;
      if (r >= cnt) continue;
      int entry = lists[e * NUM_TOKENS + r];
      int tok = entry & 0xFFFF;
      int slot = entry >> 16;
      float p = probs[tok * 2 + slot];
      float* orow = out + (size_t)tok * DIM;
#pragma unroll
      for (int in_ = 0; in_ < 4; ++in_) {
        int n = n0 + wn + in_ * 16 + col;
        float v = acc[im][in_][reg] + eb[e * DIM + n];
        atomicAdd(orow + n, p * v);  // exactly 2 adders per element
      }
    }
  }
}

extern "C" void kernel_launch(void* const* d_in, const int* in_sizes, int n_in,
                              void* d_out, int out_size, void* d_ws, size_t ws_size,
                              hipStream_t stream) {
  const float* x  = (const float*)d_in[0];  // [8192,2048]
  const float* ew = (const float*)d_in[1];  // [16384,2048]
  const float* eb = (const float*)d_in[2];  // [16384]
  const float* gw = (const float*)d_in[3];  // [8,2048]
  const float* gb = (const float*)d_in[4];  // [8]
  float* out = (float*)d_out;               // [8192,2048] fp32
  char* ws = (char*)d_ws;

  // workspace layout (needs ~96.5 MB)
  unsigned short* wb = (unsigned short*)(ws);              // 67108864 B: W bf16
  unsigned short* xb = (unsigned short*)(ws + 67108864);   // 33554432 B: x bf16
  float* probs = (float*)(ws + 100663296);                 //    65536 B: [8192,2]
  int* lists   = (int*)(ws + 100728832);                   //   262144 B: [8,8192]
  int* counts  = (int*)(ws + 100990976);                   //       32 B
  int* routed  = (int*)(ws + 100991008);                   //    32768 B: [8192]

  hipMemsetAsync(out, 0, (size_t)NUM_TOKENS * DIM * sizeof(float), stream);
  convert_w_kernel<<<(NE * DIM * DIM / 4) / 256, 256, 0, stream>>>(
      (const float4*)ew, (ushort4*)wb);
  gating_kernel<<<NUM_TOKENS / 4, 256, 0, stream>>>(x, gw, gb, xb, probs,
                                                    routed);
  build_lists_kernel<<<NE, 256, 0, stream>>>(routed, lists, counts);
  moe_gemm_kernel<<<dim3(DIM / BN, NUM_TOKENS / BM, NE), 256, 0, stream>>>(
      xb, wb, eb, probs, lists, counts, out);
}

// Round 4
// 502.811 us; speedup vs baseline: 1.7297x; 1.3480x over previous
//
#include <hip/hip_runtime.h>

#define NUM_TOKENS 8192
#define DIM 2048
#define NE 8
#define BM 128
#define BN 128
#define BK 64

typedef __bf16 bf16x8 __attribute__((ext_vector_type(8)));
typedef float f32x4 __attribute__((ext_vector_type(4)));

typedef __attribute__((address_space(1))) const void* as1_cvp;
typedef __attribute__((address_space(3))) void* as3_vp;

// fp32 -> bf16 round-to-nearest-even (manual; inputs are finite)
__device__ __forceinline__ unsigned short f2bf(float f) {
  unsigned int u = __float_as_uint(f);
  unsigned int lsb = (u >> 16) & 1u;
  u += 0x7fffu + lsb;
  return (unsigned short)(u >> 16);
}
__device__ __forceinline__ float bflo(unsigned int u) {
  return __uint_as_float(u << 16);
}
__device__ __forceinline__ float bfhi(unsigned int u) {
  return __uint_as_float(u & 0xffff0000u);
}

// ---------------- expert weights fp32 -> bf16 ----------------
__global__ __launch_bounds__(256) void convert_w_kernel(
    const float4* __restrict__ w, ushort4* __restrict__ wb) {
  int i = blockIdx.x * 256 + threadIdx.x;  // grid covers 16384*2048/4 exactly
  float4 v = w[i];
  ushort4 o;
  o.x = f2bf(v.x); o.y = f2bf(v.y); o.z = f2bf(v.z); o.w = f2bf(v.w);
  wb[i] = o;
}

// -------- gating (fp32) + x fp32->bf16; NO atomics (writes routed[t]) -------
__global__ __launch_bounds__(256) void gating_kernel(
    const float* __restrict__ x, const float* __restrict__ gw,
    const float* __restrict__ gb, unsigned short* __restrict__ xb,
    float* __restrict__ probs, int* __restrict__ routed) {
  const int wave = threadIdx.x >> 6;
  const int lane = threadIdx.x & 63;
  const int t = blockIdx.x * 4 + wave;  // one wave per token
  const float4* xrow = (const float4*)(x + (size_t)t * DIM);
  ushort4* xbrow = (ushort4*)(xb + (size_t)t * DIM);
  float acc[NE];
#pragma unroll
  for (int e = 0; e < NE; ++e) acc[e] = 0.f;
#pragma unroll
  for (int it = 0; it < DIM / (4 * 64); ++it) {  // 8 iters
    const int k4 = it * 64 + lane;
    float4 xv = xrow[k4];
    ushort4 o;
    o.x = f2bf(xv.x); o.y = f2bf(xv.y); o.z = f2bf(xv.z); o.w = f2bf(xv.w);
    xbrow[k4] = o;
#pragma unroll
    for (int e = 0; e < NE; ++e) {
      float4 wv = ((const float4*)(gw + (size_t)e * DIM))[k4];
      acc[e] += xv.x * wv.x + xv.y * wv.y + xv.z * wv.z + xv.w * wv.w;
    }
  }
#pragma unroll
  for (int e = 0; e < NE; ++e) {
#pragma unroll
    for (int off = 32; off > 0; off >>= 1)
      acc[e] += __shfl_xor(acc[e], off, 64);
  }
  if (lane == 0) {
    float p[NE];
    float mx = -1e30f;
#pragma unroll
    for (int e = 0; e < NE; ++e) {
      p[e] = acc[e] + gb[e];
      mx = fmaxf(mx, p[e]);
    }
    float s = 0.f;
#pragma unroll
    for (int e = 0; e < NE; ++e) { p[e] = __expf(p[e] - mx); s += p[e]; }
    float inv = 1.f / s;
#pragma unroll
    for (int e = 0; e < NE; ++e) p[e] *= inv;
    // top-2, ties -> lower index (matches lax.top_k)
    int e0 = 0;
#pragma unroll
    for (int e = 1; e < NE; ++e) if (p[e] > p[e0]) e0 = e;
    int e1 = (e0 == 0) ? 1 : 0;
#pragma unroll
    for (int e = 0; e < NE; ++e) if (e != e0 && p[e] > p[e1]) e1 = e;
    probs[t * 2 + 0] = p[e0];
    probs[t * 2 + 1] = p[e1];
    routed[t] = e0 | (e1 << 8);
  }
}

// ---- build per-expert token lists + COMPACT y-positions --------------------
// Block e scans all routed tokens. sc-scan: within-expert-e prefix. sb-scan:
// entries routed to experts < e -> base[e] (compact y row offset, max 16384).
__global__ __launch_bounds__(256) void build_lists_kernel(
    const int* __restrict__ routed, int* __restrict__ lists,
    int* __restrict__ counts, int* __restrict__ tokpos) {
  const int e = blockIdx.x;
  const int tid = threadIdx.x;
  __shared__ int sc[256];
  __shared__ int sb[256];
  const int base_t = tid * (NUM_TOKENS / 256);  // 32 tokens/thread
  int c = 0, cb = 0;
#pragma unroll 4
  for (int j = 0; j < NUM_TOKENS / 256; ++j) {
    int r = routed[base_t + j];
    int a0 = r & 0xff, a1 = (r >> 8) & 0xff;
    c += (a0 == e) + (a1 == e);
    cb += (a0 < e) + (a1 < e);
  }
  sc[tid] = c;
  sb[tid] = cb;
  __syncthreads();
  for (int ofs = 1; ofs < 256; ofs <<= 1) {  // inclusive Hillis-Steele scan
    int v = (tid >= ofs) ? sc[tid - ofs] : 0;
    int w = (tid >= ofs) ? sb[tid - ofs] : 0;
    __syncthreads();
    sc[tid] += v;
    sb[tid] += w;
    __syncthreads();
  }
  const int ebase = sb[255];  // total entries of experts < e  (<= 16384-cnt)
  int pos = sc[tid] - c;
#pragma unroll 4
  for (int j = 0; j < NUM_TOKENS / 256; ++j) {
    int t = base_t + j;
    int r = routed[t];
    if ((r & 0xff) == e) {
      lists[e * NUM_TOKENS + pos] = t;            // slot 0
      tokpos[2 * t] = ebase + pos;
      pos++;
    }
    if (((r >> 8) & 0xff) == e) {
      lists[e * NUM_TOKENS + pos] = t | 0x10000;  // slot 1
      tokpos[2 * t + 1] = ebase + pos;
      pos++;
    }
  }
  if (tid == 255) {
    counts[e] = sc[255];
    counts[8 + e] = ebase;
  }
}

// -------- grouped expert GEMM: y[base+r] = x[tok] @ W_e^T + b_e (bf16) -----
// LDS 16B-granule XOR swizzle (conflict-free, verified R2). Tile-region remap:
// dispatch-linear %8 == bx%8 picks the XCD (MI3xx heuristic); each XCD gets a
// fixed 4-nt group (B strip 2MB, L2-resident per expert) and walks mt in 4x4
// regions -> ~5x less L3 staging traffic.
__global__ __launch_bounds__(256) void moe_gemm_kernel(
    const unsigned short* __restrict__ xb,   // [8192,2048] bf16
    const unsigned short* __restrict__ wb,   // [16384,2048] bf16
    const float* __restrict__ eb,            // [16384]
    const float* __restrict__ probs,         // [8192,2] (fallback only)
    const int* __restrict__ lists,           // [8,8192]
    const int* __restrict__ counts,          // [0:8]=cnt, [8:16]=ybase
    unsigned short* __restrict__ y,          // [16384,2048] bf16 (use_y)
    float* __restrict__ out,                 // [8192,2048] (fallback)
    int use_y) {
  const int e = blockIdx.z;
  const int cnt = counts[e];
  const int s = blockIdx.x + 16 * blockIdx.y;  // 0..1023; s&7 == dispatch%8
  const int xcd = s & 7;
  const int j = s >> 3;                        // 0..127 within XCD
  const int R = (j >> 4) * 8 + xcd;            // region 0..63
  const int w4 = j & 15;
  const int mt = (R >> 2) * 4 + (w4 & 3);
  const int nt = (R & 3) * 4 + (w4 >> 2);
  const int m0 = mt * BM;
  if (m0 >= cnt) return;
  const int n0 = nt * BN;

  __shared__ __attribute__((aligned(16))) unsigned short As[BM * BK];
  __shared__ __attribute__((aligned(16))) unsigned short Bs[BN * BK];

  const int tid = threadIdx.x;
  const int wave = tid >> 6;
  const int lane = tid & 63;
  const int srow = lane >> 3;                       // 0..7 staging row in chunk
  const int scol = ((lane & 7) ^ srow) * 8;         // swizzled 16B-granule col

  // per-wave staging rows: wave*32 + i*8 + srow (A gathers tokens, B dense)
  const unsigned short* ag[4];
  const unsigned short* bg[4];
#pragma unroll
  for (int i = 0; i < 4; ++i) {
    int r = m0 + wave * 32 + i * 8 + srow;
    int rc = r < cnt ? r : cnt - 1;  // clamp: garbage rows never stored
    int tok = lists[e * NUM_TOKENS + rc] & 0xFFFF;
    ag[i] = xb + (size_t)tok * DIM + scol;
    int wr = e * DIM + n0 + wave * 32 + i * 8 + srow;
    bg[i] = wb + (size_t)wr * DIM + scol;
  }

  const f32x4 zero = {0.f, 0.f, 0.f, 0.f};
  f32x4 acc[4][4];
#pragma unroll
  for (int a = 0; a < 4; ++a)
#pragma unroll
    for (int b = 0; b < 4; ++b) acc[a][b] = zero;

  const int wm = (wave >> 1) * 64;  // wave's 64x64 quadrant
  const int wn = (wave & 1) * 64;
  const int frow = lane & 15;       // MFMA A/B operand row/col
  const int csel = lane >> 4;       // granule select within k-slab (0..3)
  const int swz = lane & 7;         // == row&7 for this lane's fragment rows

  for (int k0 = 0; k0 < DIM; k0 += BK) {
    __syncthreads();
#pragma unroll
    for (int i = 0; i < 4; ++i) {
      __builtin_amdgcn_global_load_lds(
          (as1_cvp)(ag[i] + k0),
          (as3_vp)(As + (wave * 32 + i * 8) * BK), 16, 0, 0);
      __builtin_amdgcn_global_load_lds(
          (as1_cvp)(bg[i] + k0),
          (as3_vp)(Bs + (wave * 32 + i * 8) * BK), 16, 0, 0);
    }
    __syncthreads();  // compiler drains vmcnt before s_barrier
#pragma unroll
    for (int kk = 0; kk < BK; kk += 32) {
      const int koff = ((((kk >> 3) | csel) ^ swz) << 3);  // swizzled element
      bf16x8 af[4], bfr[4];
#pragma unroll
      for (int im = 0; im < 4; ++im)
        af[im] = *(const bf16x8*)(As + (wm + im * 16 + frow) * BK + koff);
#pragma unroll
      for (int in_ = 0; in_ < 4; ++in_)
        bfr[in_] = *(const bf16x8*)(Bs + (wn + in_ * 16 + frow) * BK + koff);
#pragma unroll
      for (int im = 0; im < 4; ++im)
#pragma unroll
        for (int in_ = 0; in_ < 4; ++in_)
          acc[im][in_] = __builtin_amdgcn_mfma_f32_16x16x32_bf16(
              af[im], bfr[in_], acc[im][in_], 0, 0, 0);
    }
  }

  // epilogue: C/D layout col=lane&15, row=quad*4+reg (m89/m91-verified)
  const int quad = lane >> 4;
  const int col = lane & 15;
  const int ybase = counts[8 + e];  // compact row base for this expert
#pragma unroll
  for (int im = 0; im < 4; ++im) {
#pragma unroll
    for (int reg = 0; reg < 4; ++reg) {
      int r = m0 + wm + im * 16 + quad * 4 + reg;
      if (r >= cnt) continue;
      if (use_y) {
        unsigned short* yrow = y + (size_t)(ybase + r) * DIM;  // < 16384 rows
#pragma unroll
        for (int in_ = 0; in_ < 4; ++in_) {
          int n = n0 + wn + in_ * 16 + col;
          yrow[n] = f2bf(acc[im][in_][reg] + eb[e * DIM + n]);
        }
      } else {
        int entry = lists[e * NUM_TOKENS + r];
        int tok = entry & 0xFFFF;
        int slot = entry >> 16;
        float p = probs[tok * 2 + slot];
        float* orow = out + (size_t)tok * DIM;
#pragma unroll
        for (int in_ = 0; in_ < 4; ++in_) {
          int n = n0 + wn + in_ * 16 + col;
          float v = acc[im][in_][reg] + eb[e * DIM + n];
          atomicAdd(orow + n, p * v);
        }
      }
    }
  }
}

// -------- combine: out[t] = p0*y[pos0] + p1*y[pos1] (one block per token) ---
__global__ __launch_bounds__(256) void combine_kernel(
    const unsigned short* __restrict__ y, const float* __restrict__ probs,
    const int* __restrict__ tokpos, float* __restrict__ out) {
  const int t = blockIdx.x;
  const int tid = threadIdx.x;
  const int i0 = tokpos[2 * t], i1 = tokpos[2 * t + 1];
  const float p0 = probs[2 * t], p1 = probs[2 * t + 1];
  uint4 a = ((const uint4*)(y + (size_t)i0 * DIM))[tid];  // 8 bf16
  uint4 b = ((const uint4*)(y + (size_t)i1 * DIM))[tid];
  float4 o0, o1;
  o0.x = p0 * bflo(a.x) + p1 * bflo(b.x);
  o0.y = p0 * bfhi(a.x) + p1 * bfhi(b.x);
  o0.z = p0 * bflo(a.y) + p1 * bflo(b.y);
  o0.w = p0 * bfhi(a.y) + p1 * bfhi(b.y);
  o1.x = p0 * bflo(a.z) + p1 * bflo(b.z);
  o1.y = p0 * bfhi(a.z) + p1 * bfhi(b.z);
  o1.z = p0 * bflo(a.w) + p1 * bflo(b.w);
  o1.w = p0 * bfhi(a.w) + p1 * bfhi(b.w);
  float4* orow = (float4*)(out + (size_t)t * DIM);
  orow[2 * tid] = o0;
  orow[2 * tid + 1] = o1;
}

extern "C" void kernel_launch(void* const* d_in, const int* in_sizes, int n_in,
                              void* d_out, int out_size, void* d_ws, size_t ws_size,
                              hipStream_t stream) {
  const float* x  = (const float*)d_in[0];  // [8192,2048]
  const float* ew = (const float*)d_in[1];  // [16384,2048]
  const float* eb = (const float*)d_in[2];  // [16384]
  const float* gw = (const float*)d_in[3];  // [8,2048]
  const float* gb = (const float*)d_in[4];  // [8]
  float* out = (float*)d_out;               // [8192,2048] fp32
  char* p = (char*)d_ws;

  const size_t NEED = 67108864ull + 33554432ull + 67108864ull + 65536ull +
                      262144ull + 64ull + 32768ull + 65536ull;  // ~160.6 MiB
  const int use_y = (ws_size >= NEED) ? 1 : 0;

  unsigned short* wb = (unsigned short*)p; p += 67108864;
  unsigned short* xb = (unsigned short*)p; p += 33554432;
  unsigned short* y = nullptr;
  if (use_y) { y = (unsigned short*)p; p += 67108864; }
  float* probs = (float*)p; p += 65536;
  int* lists   = (int*)p;   p += 262144;
  int* counts  = (int*)p;   p += 64;
  int* routed  = (int*)p;   p += 32768;
  int* tokpos  = (int*)p;   p += 65536;

  if (!use_y)
    hipMemsetAsync(out, 0, (size_t)NUM_TOKENS * DIM * sizeof(float), stream);
  convert_w_kernel<<<(NE * DIM * DIM / 4) / 256, 256, 0, stream>>>(
      (const float4*)ew, (ushort4*)wb);
  gating_kernel<<<NUM_TOKENS / 4, 256, 0, stream>>>(x, gw, gb, xb, probs,
                                                    routed);
  build_lists_kernel<<<NE, 256, 0, stream>>>(routed, lists, counts, tokpos);
  moe_gemm_kernel<<<dim3(DIM / BN, NUM_TOKENS / BM, NE), 256, 0, stream>>>(
      xb, wb, eb, probs, lists, counts, y, out, use_y);
  if (use_y)
    combine_kernel<<<NUM_TOKENS, 256, 0, stream>>>(y, probs, tokpos, out);
}